// Round 14
// baseline (5099.812 us; speedup 1.0000x reference)
//
#include <hip/hip_runtime.h>
#include <hip/hip_bf16.h>
#include <math.h>

#define BB 2
#define LL 8192
#define DD 512
#define NLAYER 8
#define TD 1536   // 3*D
#define HD 2048   // 4*D
#define NFFT 16384
#define NHALF 8192
#define HSTR 4160  // padded length of stored half-spectrum (k in [0,4096])
#define BLD (BB*LL*DD)
#define BLH ((size_t)BB*LL*HD)

typedef unsigned short u16;
typedef unsigned int   u32;
typedef __bf16 bf16x8 __attribute__((ext_vector_type(8)));
typedef float  f32x4  __attribute__((ext_vector_type(4)));

__device__ __forceinline__ u16 f2bf(float f) {
    union { float f; u32 u; } v; v.f = f;
    u32 r = v.u + 0x7FFF + ((v.u >> 16) & 1);   // RNE
    return (u16)(r >> 16);
}
__device__ __forceinline__ float bf2f(u16 h) {
    union { u32 u; float f; } v; v.u = (u32)h << 16; return v.f;
}

__device__ __forceinline__ void async_g2l_16(const u16* g, u16* l) {
    __builtin_amdgcn_global_load_lds(
        (const __attribute__((address_space(1))) void*)g,
        (__attribute__((address_space(3))) void*)l,
        16, 0, 0);
}

__device__ __forceinline__ float2 cmul(float2 a, float2 b) {
    return make_float2(a.x * b.x - a.y * b.y, a.x * b.y + a.y * b.x);
}
__device__ __forceinline__ float2 cmulc(float2 a, float2 b) {  // a*conj(b)
    return make_float2(a.x * b.x + a.y * b.y, a.y * b.x - a.x * b.y);
}
__device__ __forceinline__ float2 cadd(float2 a, float2 b) {
    return make_float2(a.x + b.x, a.y + b.y);
}
__device__ __forceinline__ float2 csub(float2 a, float2 b) {
    return make_float2(a.x - b.x, a.y - b.y);
}
// reverse 6 base-4 digits of a 12-bit index
__device__ __forceinline__ int drev12(int m) {
    return ((m & 3) << 10) | (((m >> 2) & 3) << 8) | (((m >> 4) & 3) << 6) |
           (((m >> 6) & 3) << 4) | (((m >> 8) & 3) << 2) | ((m >> 10) & 3);
}
// frequency k (0..8191) -> LDS position after fwd FFT (r2-DIF + 6 r4-DIF per half)
__device__ __forceinline__ int perm8k(int k) {
    return ((k & 1) << 12) + drev12(k >> 1);
}
// LDS bank swizzle (float2 elements): XOR low 4 bits with hash of high bits.
__device__ __forceinline__ int swz(int i) {
    return i ^ (((i >> 4) ^ (i >> 8)) & 15);
}
#define LDX(arr, i) arr[swz(i)]

// ---------------- twiddle table: tw[k] = exp(-2*pi*i*k/NFFT), k in [0,N) ----
__global__ void twiddle_kernel(float* twf) {
    int k = blockIdx.x * 256 + threadIdx.x;
    if (k < NFFT) {
        double ang = -2.0 * M_PI * (double)k / (double)NFFT;
        twf[2 * k]     = (float)cos(ang);
        twf[2 * k + 1] = (float)sin(ang);
    }
}

// ---------------- embedding ------------------------------------------------
__global__ void embed_kernel(const int* __restrict__ ids,
                             const float* __restrict__ emb,
                             float* __restrict__ u) {
    int i = blockIdx.x * 256 + threadIdx.x;
    if (i < BLD) {
        int row = i >> 9;
        int d   = i & (DD - 1);
        u[i] = emb[ids[row] * DD + d];
    }
}

// ------------- weight prep: f32 [K,N] -> bf16 hi/lo [N,K] -------------------
__global__ __launch_bounds__(256)
void wprep_kernel(const float* __restrict__ W, u16* __restrict__ WtH,
                  u16* __restrict__ WtL, int K, int N, long srcStride, long dstStride) {
    __shared__ float t[64][65];
    const float* src = W + (size_t)blockIdx.z * srcStride;
    u16* dsth = WtH + (size_t)blockIdx.z * dstStride;
    u16* dstl = WtL + (size_t)blockIdx.z * dstStride;
    int n0 = blockIdx.x * 64, k0 = blockIdx.y * 64;
    int tc = threadIdx.x & 63, tr = threadIdx.x >> 6;
    for (int r = tr; r < 64; r += 4)
        t[r][tc] = src[(size_t)(k0 + r) * N + n0 + tc];
    __syncthreads();
    for (int r = tr; r < 64; r += 4) {
        float v = t[tc][r];
        u16 h = f2bf(v);
        dsth[(size_t)(n0 + r) * K + k0 + tc] = h;
        dstl[(size_t)(n0 + r) * K + k0 + tc] = f2bf(v - bf2f(h));
    }
}

// ---------------- layernorm (row length 512), standalone (layer-0 ln1) -----
template<int MODE>   // 0: f32 out. 1: bf16 hi/lo planes.
__global__ __launch_bounds__(128)
void ln_kernel(const float* __restrict__ x, void* __restrict__ out,
               void* __restrict__ outL,
               const float* __restrict__ g, const float* __restrict__ b) {
    int row = blockIdx.x;
    const float4* xr = (const float4*)(x + (size_t)row * DD);
    int t = threadIdx.x;
    float4 v = xr[t];
    float s  = v.x + v.y + v.z + v.w;
    float ss = v.x * v.x + v.y * v.y + v.z * v.z + v.w * v.w;
    for (int off = 32; off; off >>= 1) {
        s  += __shfl_down(s, off);
        ss += __shfl_down(ss, off);
    }
    __shared__ float sm[4];
    if ((t & 63) == 0) { sm[(t >> 6) * 2] = s; sm[(t >> 6) * 2 + 1] = ss; }
    __syncthreads();
    float S = sm[0] + sm[2], SS = sm[1] + sm[3];
    float mu  = S * (1.0f / DD);
    float var = SS * (1.0f / DD) - mu * mu;
    float rs  = rsqrtf(var + 1e-5f);
    float4 gg = ((const float4*)g)[t];
    float4 bb = ((const float4*)b)[t];
    float o[4];
    o[0] = (v.x - mu) * rs * gg.x + bb.x;
    o[1] = (v.y - mu) * rs * gg.y + bb.y;
    o[2] = (v.z - mu) * rs * gg.z + bb.z;
    o[3] = (v.w - mu) * rs * gg.w + bb.w;
    if (MODE == 1) {
        u16 h[4], lo[4];
#pragma unroll
        for (int i = 0; i < 4; i++) {
            h[i]  = f2bf(o[i]);
            lo[i] = f2bf(o[i] - bf2f(h[i]));
        }
        uint2 ph, pl;
        ph.x = (u32)h[0] | ((u32)h[1] << 16);  ph.y = (u32)h[2] | ((u32)h[3] << 16);
        pl.x = (u32)lo[0] | ((u32)lo[1] << 16); pl.y = (u32)lo[2] | ((u32)lo[3] << 16);
        ((uint2*)((u16*)out  + (size_t)row * DD))[t] = ph;
        ((uint2*)((u16*)outL + (size_t)row * DD))[t] = pl;
    } else {
        float4 of = {o[0], o[1], o[2], o[3]};
        ((float4*)((float*)out + (size_t)row * DD))[t] = of;
    }
}

// ---------------- gelu (tanh approximation, JAX default) -------------------
__device__ __forceinline__ float gelu_f(float x) {
    float x3 = x * x * x;
    float t  = tanhf(0.79788456080286541f * (x + 0.044715f * x3));
    return 0.5f * x * (1.0f + t);
}

// ------- compensated bf16 MFMA GEMM: C = (Ah+Al) @ (Bh+Bl)^T + bias --------
// PASSES=3: ah*bh + al*bh + ah*bl.  PASSES=2: ah*bh + al*bh.
// XCD-aware block swizzle (T1).  Used for Win (OUT=0) and W1 (OUT=1,GELU).
template<int OUT, bool GELU, int PASSES>
__global__ __launch_bounds__(256)
void mfma_gemm3(const u16* __restrict__ Ah, const u16* __restrict__ Al,
                const u16* __restrict__ Bh, const u16* __restrict__ Bl,
                const float* __restrict__ bias,
                float* __restrict__ Cf, u16* __restrict__ Ch, u16* __restrict__ Cl,
                int M, int N, int K) {
    __shared__ u16 AsH[128 * 32];
    __shared__ u16 AsL[128 * 32];
    __shared__ u16 BsH[128 * 32];
    __shared__ u16 BsL[(PASSES == 3) ? 128 * 32 : 8];
    int nwg  = gridDim.x * gridDim.y;
    int wgid = blockIdx.y * gridDim.x + blockIdx.x;
    int nid  = (wgid & 7) * (nwg >> 3) + (wgid >> 3);
    int bx = nid % gridDim.x, by = nid / gridDim.x;
    int m0 = by * 128, n0 = bx * 128;
    int tid = threadIdx.x;
    int w = tid >> 6, l = tid & 63;
    int wr = w >> 1, wc = w & 1;

    int ch0 = w * 2, ch1 = ch0 + 1;
    size_t offA0 = (size_t)(m0 + ch0 * 16 + (l >> 2)) * K + (l & 3) * 8;
    size_t offA1 = (size_t)(m0 + ch1 * 16 + (l >> 2)) * K + (l & 3) * 8;
    size_t offB0 = (size_t)(n0 + ch0 * 16 + (l >> 2)) * K + (l & 3) * 8;
    size_t offB1 = (size_t)(n0 + ch1 * 16 + (l >> 2)) * K + (l & 3) * 8;

    f32x4 acc[4][4] = {};
    int arow = wr * 64 + (l & 15);
    int brow = wc * 64 + (l & 15);
    int kc   = (l >> 4) * 8;

    for (int k0 = 0; k0 < K; k0 += 32) {
        async_g2l_16(Ah + offA0 + k0, &AsH[ch0 * 512]);
        async_g2l_16(Ah + offA1 + k0, &AsH[ch1 * 512]);
        async_g2l_16(Al + offA0 + k0, &AsL[ch0 * 512]);
        async_g2l_16(Al + offA1 + k0, &AsL[ch1 * 512]);
        async_g2l_16(Bh + offB0 + k0, &BsH[ch0 * 512]);
        async_g2l_16(Bh + offB1 + k0, &BsH[ch1 * 512]);
        if (PASSES == 3) {
            async_g2l_16(Bl + offB0 + k0, &BsL[ch0 * 512]);
            async_g2l_16(Bl + offB1 + k0, &BsL[ch1 * 512]);
        }
        __syncthreads();
        bf16x8 ah[4], al[4], bh[4], bl[4];
#pragma unroll
        for (int i = 0; i < 4; i++) {
            ah[i] = *(const bf16x8*)&AsH[(arow + i * 16) * 32 + kc];
            al[i] = *(const bf16x8*)&AsL[(arow + i * 16) * 32 + kc];
            bh[i] = *(const bf16x8*)&BsH[(brow + i * 16) * 32 + kc];
            if (PASSES == 3)
                bl[i] = *(const bf16x8*)&BsL[(brow + i * 16) * 32 + kc];
        }
#pragma unroll
        for (int mi = 0; mi < 4; mi++)
#pragma unroll
            for (int ni = 0; ni < 4; ni++) {
                acc[mi][ni] = __builtin_amdgcn_mfma_f32_16x16x32_bf16(
                    ah[mi], bh[ni], acc[mi][ni], 0, 0, 0);
                acc[mi][ni] = __builtin_amdgcn_mfma_f32_16x16x32_bf16(
                    al[mi], bh[ni], acc[mi][ni], 0, 0, 0);
                if (PASSES == 3)
                    acc[mi][ni] = __builtin_amdgcn_mfma_f32_16x16x32_bf16(
                        ah[mi], bl[ni], acc[mi][ni], 0, 0, 0);
            }
        __syncthreads();
    }

    int lr = l >> 4, lc = l & 15;
#pragma unroll
    for (int mi = 0; mi < 4; mi++) {
#pragma unroll
        for (int ni = 0; ni < 4; ni++) {
            int col = n0 + wc * 64 + ni * 16 + lc;
            float bv = bias[col];
            int rowb = m0 + wr * 64 + mi * 16 + lr * 4;
#pragma unroll
            for (int r = 0; r < 4; r++) {
                float v = acc[mi][ni][r] + bv;
                if (GELU) v = gelu_f(v);
                size_t off = (size_t)(rowb + r) * N + col;
                if (OUT == 0) {
                    Cf[off] = v;
                } else if (OUT == 1) {
                    u16 h = f2bf(v);
                    Ch[off] = h;
                    Cl[off] = f2bf(v - bf2f(h));
                } else {
                    Cf[off] += v;
                }
            }
        }
    }
}

// ---- fused N=512 GEMM + residual + LayerNorm (Wout+ln2, W2+ln1' / lnf) ----
// Tile 64(M) x 512(N) = full rows; 512 threads = 8 waves, wave w owns cols
// [w*64, w*64+64).  2-pass hi/lo (ah*bh + al*bh).  Epilogue: v = (acc+bias)
// + u_old (same association as split version -> residual bit-exact), write u,
// block-local LN, write z (bf16 hi/lo) or f32 final output.
template<int ZMODE>  // 1: zh/zl bf16 planes; 0: f32 out (final lnf)
__global__ __launch_bounds__(512)
void gemm_ln_kernel(const u16* __restrict__ Ah, const u16* __restrict__ Al,
                    const u16* __restrict__ Bh, const float* __restrict__ bias,
                    float* __restrict__ u, void* __restrict__ zOut,
                    void* __restrict__ zOutL, const float* __restrict__ g,
                    const float* __restrict__ bvec, int K) {
    __shared__ u16 AsH[64 * 32];
    __shared__ u16 AsL[64 * 32];
    __shared__ u16 BsH[512 * 32];
    __shared__ float redS[64][8];
    __shared__ float redQ[64][8];
    __shared__ float2 murs[64];
    int m0 = blockIdx.x * 64;
    int tid = threadIdx.x;
    int w = tid >> 6, l = tid & 63;
    int lc = l & 15, lr = l >> 4;
    int kc = lr * 8;
    int rr = l >> 2, kk = (l & 3) * 8;   // staging lane map within a 16x32 chunk

    f32x4 acc[4][4] = {};
    for (int k0 = 0; k0 < K; k0 += 32) {
        // 40 chunks of 1 KiB: 4 AsH + 4 AsL + 32 BsH; wave w stages w*5..w*5+4
#pragma unroll
        for (int i = 0; i < 5; i++) {
            int ch = w * 5 + i;
            if (ch < 4) {
                async_g2l_16(Ah + (size_t)(m0 + ch * 16 + rr) * K + k0 + kk,
                             &AsH[ch * 512]);
            } else if (ch < 8) {
                async_g2l_16(Al + (size_t)(m0 + (ch - 4) * 16 + rr) * K + k0 + kk,
                             &AsL[(ch - 4) * 512]);
            } else {
                async_g2l_16(Bh + (size_t)((ch - 8) * 16 + rr) * K + k0 + kk,
                             &BsH[(ch - 8) * 512]);
            }
        }
        __syncthreads();
        bf16x8 ah[4], al[4], bh[4];
#pragma unroll
        for (int i = 0; i < 4; i++) {
            ah[i] = *(const bf16x8*)&AsH[(i * 16 + lc) * 32 + kc];
            al[i] = *(const bf16x8*)&AsL[(i * 16 + lc) * 32 + kc];
            bh[i] = *(const bf16x8*)&BsH[(w * 64 + i * 16 + lc) * 32 + kc];
        }
#pragma unroll
        for (int mi = 0; mi < 4; mi++)
#pragma unroll
            for (int ni = 0; ni < 4; ni++) {
                acc[mi][ni] = __builtin_amdgcn_mfma_f32_16x16x32_bf16(
                    ah[mi], bh[ni], acc[mi][ni], 0, 0, 0);
                acc[mi][ni] = __builtin_amdgcn_mfma_f32_16x16x32_bf16(
                    al[mi], bh[ni], acc[mi][ni], 0, 0, 0);
            }
        __syncthreads();
    }

    // epilogue: residual add + u write + per-row partial sums
    float sP[4][4], qP[4][4];
#pragma unroll
    for (int mi = 0; mi < 4; mi++)
#pragma unroll
        for (int r = 0; r < 4; r++) { sP[mi][r] = 0.f; qP[mi][r] = 0.f; }
#pragma unroll
    for (int mi = 0; mi < 4; mi++) {
#pragma unroll
        for (int ni = 0; ni < 4; ni++) {
            int col = w * 64 + ni * 16 + lc;
            float bv = bias[col];
#pragma unroll
            for (int r = 0; r < 4; r++) {
                int row = mi * 16 + lr * 4 + r;
                size_t off = (size_t)(m0 + row) * DD + col;
                float v = (acc[mi][ni][r] + bv) + u[off];
                u[off] = v;
                acc[mi][ni][r] = v;
                sP[mi][r] += v;
                qP[mi][r] += v * v;
            }
        }
    }
    // 16-lane xor-reduce within each lr group (lanes differ in low 4 bits)
#pragma unroll
    for (int m = 1; m < 16; m <<= 1)
#pragma unroll
        for (int mi = 0; mi < 4; mi++)
#pragma unroll
            for (int r = 0; r < 4; r++) {
                sP[mi][r] += __shfl_xor(sP[mi][r], m);
                qP[mi][r] += __shfl_xor(qP[mi][r], m);
            }
    {   // lane lc writes row (mi=lc>>2, r=lc&3) of its lr group
        int mi = lc >> 2, r = lc & 3;
        int row = mi * 16 + lr * 4 + r;
        redS[row][w] = sP[mi][r];
        redQ[row][w] = qP[mi][r];
    }
    __syncthreads();
    if (tid < 64) {
        float S = 0.f, Q = 0.f;
#pragma unroll
        for (int ww = 0; ww < 8; ww++) { S += redS[tid][ww]; Q += redQ[tid][ww]; }
        float mu  = S * (1.0f / DD);
        float var = Q * (1.0f / DD) - mu * mu;
        murs[tid] = make_float2(mu, rsqrtf(var + 1e-5f));
    }
    __syncthreads();
#pragma unroll
    for (int mi = 0; mi < 4; mi++) {
#pragma unroll
        for (int r = 0; r < 4; r++) {
            int row = mi * 16 + lr * 4 + r;
            float2 mr = murs[row];
#pragma unroll
            for (int ni = 0; ni < 4; ni++) {
                int col = w * 64 + ni * 16 + lc;
                float z = (acc[mi][ni][r] - mr.x) * mr.y * g[col] + bvec[col];
                size_t off = (size_t)(m0 + row) * DD + col;
                if (ZMODE == 1) {
                    u16 h = f2bf(z);
                    ((u16*)zOut)[off]  = h;
                    ((u16*)zOutL)[off] = f2bf(z - bf2f(h));
                } else {
                    ((float*)zOut)[off] = z;
                }
            }
        }
    }
}

// ---------------- short conv (k=3 causal) + gating + transpose -------------
__global__ __launch_bounds__(256)
void conv_gate_kernel(const float* __restrict__ p, const float* __restrict__ cw,
                      const float* __restrict__ cb, float* __restrict__ vg,
                      float* __restrict__ x2s) {
    __shared__ float tvg[64][65];
    __shared__ float tx2[64][65];
    int b = blockIdx.z, c0 = blockIdx.y * 64, l0 = blockIdx.x * 64;
    int tc = threadIdx.x & 63, tr = threadIdx.x >> 6;
    const float* pb = p + (size_t)b * LL * TD;
    int cx2 = c0 + tc;
    int cx1 = DD + c0 + tc;
    int cv  = 2 * DD + c0 + tc;
    float w20 = cw[cx2 * 3], w21 = cw[cx2 * 3 + 1], w22 = cw[cx2 * 3 + 2], bx2 = cb[cx2];
    float w10 = cw[cx1 * 3], w11 = cw[cx1 * 3 + 1], w12 = cw[cx1 * 3 + 2], bx1 = cb[cx1];
    float wv0 = cw[cv * 3],  wv1 = cw[cv * 3 + 1],  wv2 = cw[cv * 3 + 2],  bv  = cb[cv];
    for (int r = tr; r < 64; r += 4) {
        int l = l0 + r;
        size_t o0 = (size_t)l * TD;
        float p2a = (l >= 2) ? pb[o0 - 2 * TD + cx2] : 0.f;
        float p1a = (l >= 1) ? pb[o0 - TD + cx2] : 0.f;
        float p0a = pb[o0 + cx2];
        float p2b = (l >= 2) ? pb[o0 - 2 * TD + cx1] : 0.f;
        float p1b = (l >= 1) ? pb[o0 - TD + cx1] : 0.f;
        float p0b = pb[o0 + cx1];
        float p2c = (l >= 2) ? pb[o0 - 2 * TD + cv] : 0.f;
        float p1c = (l >= 1) ? pb[o0 - TD + cv] : 0.f;
        float p0c = pb[o0 + cv];
        float x2v = w20 * p2a + w21 * p1a + w22 * p0a + bx2;
        float x1v = w10 * p2b + w11 * p1b + w12 * p0b + bx1;
        float vv  = wv0 * p2c + wv1 * p1c + wv2 * p0c + bv;
        tx2[r][tc] = x2v;
        tvg[r][tc] = vv * x1v;
    }
    __syncthreads();
    for (int r = tr; r < 64; r += 4) {
        size_t o = ((size_t)b * DD + c0 + r) * LL + l0 + tc;
        vg[o]  = tvg[tc][r];
        x2s[o] = tx2[tc][r];
    }
}

// -------- y transpose: f32 [B,D,L] -> bf16 hi/lo [B*L, D] ------------------
__global__ __launch_bounds__(256)
void ytr_kernel(const float* __restrict__ yg, u16* __restrict__ yh,
                u16* __restrict__ yl) {
    __shared__ float t[64][65];
    int b = blockIdx.z, c0 = blockIdx.y * 64, l0 = blockIdx.x * 64;
    int tc = threadIdx.x & 63, tr = threadIdx.x >> 6;
    for (int r = tr; r < 64; r += 4)
        t[r][tc] = yg[((size_t)b * DD + c0 + r) * LL + l0 + tc];
    __syncthreads();
    for (int r = tr; r < 64; r += 4) {
        float v = t[tc][r];
        u16 h = f2bf(v);
        size_t o = ((size_t)(b * LL + l0 + r)) * DD + c0 + tc;
        yh[o] = h;
        yl[o] = f2bf(v - bf2f(h));
    }
}

// ======== 8192-pt complex FFT in 64 KiB LDS (r2c half-length core) =========
__device__ __forceinline__ void fft8192_fwd(float2* ld, const float2* __restrict__ tw, int tid) {
    __syncthreads();
    for (int n = tid; n < 4096; n += 1024) {
        float2 a = LDX(ld, n), b = LDX(ld, n + 4096);
        LDX(ld, n) = cadd(a, b);
        float2 d = csub(a, b);
        LDX(ld, n + 4096) = n ? cmul(d, tw[2 * n]) : d;   // tw8192[n] = tw[2n]
    }
    for (int s = 0; s < 6; s++) {
        int lm = 12 - 2 * s, lq = lm - 2;
        int Q = 1 << lq;
        __syncthreads();
        for (int g = tid; g < 2048; g += 1024) {
            int half = g >> 10, gg = g & 1023;
            int j = gg & (Q - 1);
            int base = (half << 12) + ((gg >> lq) << lm) + j;
            float2 x0 = LDX(ld, base), x1 = LDX(ld, base + Q);
            float2 x2 = LDX(ld, base + 2 * Q), x3 = LDX(ld, base + 3 * Q);
            float2 a = cadd(x0, x2), b = csub(x0, x2);
            float2 c = cadd(x1, x3), d = csub(x1, x3);
            float2 mid = make_float2(d.y, -d.x);          // -i*d
            float2 u0 = cadd(a, c);
            float2 u1 = cadd(b, mid);
            float2 u2 = csub(a, c);
            float2 u3 = csub(b, mid);
            int e = j << (2 * s);                          // relative to N'=4096
            if (e) {                                       // tw4096[e] = tw[4e]
                u1 = cmul(u1, tw[4 * e]);
                u2 = cmul(u2, tw[8 * e]);
                u3 = cmul(u3, tw[12 * e]);
            }
            LDX(ld, base) = u0; LDX(ld, base + Q) = u1;
            LDX(ld, base + 2 * Q) = u2; LDX(ld, base + 3 * Q) = u3;
        }
    }
    __syncthreads();
}

__device__ __forceinline__ void fft8192_inv(float2* ld, const float2* __restrict__ tw, int tid) {
    for (int s = 5; s >= 0; s--) {
        int lm = 12 - 2 * s, lq = lm - 2;
        int Q = 1 << lq;
        __syncthreads();
        for (int g = tid; g < 2048; g += 1024) {
            int half = g >> 10, gg = g & 1023;
            int j = gg & (Q - 1);
            int base = (half << 12) + ((gg >> lq) << lm) + j;
            int e = j << (2 * s);
            float2 v0 = LDX(ld, base);
            float2 v1 = LDX(ld, base + Q), v2 = LDX(ld, base + 2 * Q), v3 = LDX(ld, base + 3 * Q);
            if (e) {
                v1 = cmulc(v1, tw[4 * e]);
                v2 = cmulc(v2, tw[8 * e]);
                v3 = cmulc(v3, tw[12 * e]);
            }
            float2 a = cadd(v0, v2), b = csub(v0, v2);
            float2 c = cadd(v1, v3), d = csub(v1, v3);
            float2 id = make_float2(-d.y, d.x);           // +i*d
            LDX(ld, base)         = cadd(a, c);
            LDX(ld, base + Q)     = cadd(b, id);
            LDX(ld, base + 2 * Q) = csub(a, c);
            LDX(ld, base + 3 * Q) = csub(b, id);
        }
    }
    __syncthreads();
    for (int n = tid; n < 4096; n += 1024) {
        float2 a = LDX(ld, n);
        float2 b = LDX(ld, n + 4096);
        if (n) b = cmulc(b, tw[2 * n]);
        LDX(ld, n) = cadd(a, b);
        LDX(ld, n + 4096) = csub(a, b);
    }
    __syncthreads();
}

// -------- filter FFT (r2c): store only k in [0,4096] of Ha=H[k], Hb=H[k+8192]
__global__ __launch_bounds__(1024, 8)
void hf_kernel(const float* __restrict__ h, float2* __restrict__ HfA,
               float2* __restrict__ HfB, const float* __restrict__ twf) {
    __shared__ float2 ld[NHALF];  // 64 KiB -> 2 blocks/CU
    int c = blockIdx.x;
    const float2* hp = (const float2*)(h + (size_t)c * LL);
    const float2* tw = (const float2*)twf;
    int tid = threadIdx.x;
    for (int n = tid; n < 4096; n += 1024) LDX(ld, n) = hp[n];     // z = h[2n]+i*h[2n+1]
    for (int n = 4096 + tid; n < NHALF; n += 1024) LDX(ld, n) = make_float2(0.f, 0.f);
    fft8192_fwd(ld, tw, tid);
    float2* oa = HfA + (size_t)c * HSTR;
    float2* ob = HfB + (size_t)c * HSTR;
    for (int k = tid; k <= 4096; k += 1024) {
        int kc = (NHALF - k) & (NHALF - 1);
        int p = perm8k(k), pc = perm8k(kc);
        float2 A = LDX(ld, p), B = LDX(ld, pc);
        float2 E = make_float2(0.5f * (A.x + B.x), 0.5f * (A.y - B.y));
        float2 O = make_float2(0.5f * (A.y + B.y), -0.5f * (A.x - B.x));
        float2 t = tw[k];
        float2 tO = cmul(t, O);
        oa[k] = cadd(E, tO);   // H[k]
        ob[k] = csub(E, tO);   // H[k+8192]
    }
}

// ------- FFT convolution (r2c), 1 channel/block + skip + output gate -------
__global__ __launch_bounds__(1024, 8)
void fftconv_kernel(const float* __restrict__ vg, const float* __restrict__ x2s,
                    const float2* __restrict__ HfA, const float2* __restrict__ HfB,
                    const float* __restrict__ Db, const float* __restrict__ twf,
                    float* __restrict__ yg) {
    __shared__ float2 ld[NHALF];  // 64 KiB -> 2 blocks/CU
    int bc = blockIdx.x;                  // b * DD + c
    int c  = bc & (DD - 1);
    const float2* vp  = (const float2*)(vg  + (size_t)bc * LL);
    const float2* x2p = (const float2*)(x2s + (size_t)bc * LL);
    float2*       op  = (float2*)(yg + (size_t)bc * LL);
    const float2* tw = (const float2*)twf;
    int tid = threadIdx.x;
    float2 vv[4];
#pragma unroll
    for (int q = 0; q < 4; q++) {
        int n = tid + q * 1024;
        vv[q] = vp[n];
        LDX(ld, n) = vv[q];               // z = v[2n]+i*v[2n+1]
    }
#pragma unroll
    for (int q = 0; q < 4; q++) LDX(ld, tid + 4096 + q * 1024) = make_float2(0.f, 0.f);
    fft8192_fwd(ld, tw, tid);
    const float2* Ha = HfA + (size_t)c * HSTR;
    const float2* Hb = HfB + (size_t)c * HSTR;
    for (int k = tid; k <= 4096; k += 1024) {
        int kc = (NHALF - k) & (NHALF - 1);
        int p = perm8k(k), pc = perm8k(kc);
        float2 A = LDX(ld, p), B = LDX(ld, pc);
        float2 E = make_float2(0.5f * (A.x + B.x), 0.5f * (A.y - B.y));
        float2 O = make_float2(0.5f * (A.y + B.y), -0.5f * (A.x - B.x));
        float2 t = tw[k];
        float2 tO = cmul(t, O);
        float2 X1 = cadd(E, tO);           // X[k]
        float2 X2 = csub(E, tO);           // X[k+8192]
        float2 Hak = Ha[k], Hbk = Hb[k];
        float2 Y1 = cmul(X1, Hak);
        float2 Y2 = cmul(X2, Hbk);
        float2 S  = make_float2(0.5f * (Y1.x + Y2.x), 0.5f * (Y1.y + Y2.y));
        float2 Dd = make_float2(0.5f * (Y1.x - Y2.x), 0.5f * (Y1.y - Y2.y));
        // W[k] = S + i*conj(t)*Dd ;  i*conj(t) = (t.y, t.x)
        LDX(ld, p) = cadd(S, cmul(make_float2(t.y, t.x), Dd));
        if (kc != k) {
            float2 X1c = make_float2(X2.x, -X2.y);   // X[kc]      = conj(X[k+8192])
            float2 X2c = make_float2(X1.x, -X1.y);   // X[kc+8192] = conj(X[k])
            float2 Y1c = cmulc(X1c, Hbk);            // Ha[kc]=conj(Hb[k])
            float2 Y2c = cmulc(X2c, Hak);            // Hb[kc]=conj(Ha[k])
            float2 Sc = make_float2(0.5f * (Y1c.x + Y2c.x), 0.5f * (Y1c.y + Y2c.y));
            float2 Dc = make_float2(0.5f * (Y1c.x - Y2c.x), 0.5f * (Y1c.y - Y2c.y));
            // i*conj(t_kc) = -i*t = (t.y, -t.x)
            LDX(ld, pc) = cadd(Sc, cmul(make_float2(t.y, -t.x), Dc));
        }
    }
    fft8192_inv(ld, tw, tid);
    float db = Db[c];
    const float inv = 1.0f / (float)NHALF;
#pragma unroll
    for (int q = 0; q < 4; q++) {
        int n = tid + q * 1024;
        float2 w  = LDX(ld, n);
        float2 xx = x2p[n];
        float y0 = w.x * inv + vv[q].x * db;
        float y1 = w.y * inv + vv[q].y * db;
        op[n] = make_float2(y0 * xx.x, y1 * xx.y);
    }
}

// ---------------------------------------------------------------------------
extern "C" void kernel_launch(void* const* d_in, const int* in_sizes, int n_in,
                              void* d_out, int out_size, void* d_ws, size_t ws_size,
                              hipStream_t stream) {
    const int*   ids   = (const int*)  d_in[0];
    const float* emb   = (const float*)d_in[1];
    const float* ln1_g = (const float*)d_in[2];
    const float* ln1_b = (const float*)d_in[3];
    const float* Win   = (const float*)d_in[4];
    const float* bin_  = (const float*)d_in[5];
    const float* convw = (const float*)d_in[6];
    const float* convb = (const float*)d_in[7];
    const float* hflt  = (const float*)d_in[8];
    const float* Db    = (const float*)d_in[9];
    const float* Wout  = (const float*)d_in[10];
    const float* bout  = (const float*)d_in[11];
    const float* ln2_g = (const float*)d_in[12];
    const float* ln2_b = (const float*)d_in[13];
    const float* W1    = (const float*)d_in[14];
    const float* b1    = (const float*)d_in[15];
    const float* W2    = (const float*)d_in[16];
    const float* b2    = (const float*)d_in[17];
    const float* lnf_g = (const float*)d_in[18];
    const float* lnf_b = (const float*)d_in[19];

    char* p_ = (char*)d_ws;
    auto alloc = [&](size_t bytes) {
        char* r = p_; p_ += (bytes + 255) & ~(size_t)255; return r;
    };
    float* u   = (float*)alloc((size_t)BLD * 4);
    u16* zh    = (u16*)  alloc((size_t)BLD * 2);
    u16* zl    = (u16*)  alloc((size_t)BLD * 2);
    char* uni  = alloc(2 * BLH * 2);      // pf (f32 3*BLD) | yg (f32 BLD) | hmid hi/lo
    float* pf  = (float*)uni;
    float* yg  = (float*)uni;
    u16* hmh   = (u16*)uni;
    u16* hml   = hmh + BLH;
    float* vg  = (float*)alloc((size_t)BLD * 4);
    float* x2s = (float*)alloc((size_t)BLD * 4);
    u16* yh    = (u16*)  alloc((size_t)BLD * 2);
    u16* yl    = (u16*)  alloc((size_t)BLD * 2);
    float2* HfA = (float2*)alloc((size_t)DD * HSTR * 8);
    float2* HfB = (float2*)alloc((size_t)DD * HSTR * 8);
    float* tw  = (float*)alloc((size_t)2 * NFFT * 4);
    u16* WtInH = (u16*)alloc((size_t)NLAYER * TD * DD * 2);
    u16* WtInL = (u16*)alloc((size_t)NLAYER * TD * DD * 2);
    u16* WtOutH= (u16*)alloc((size_t)NLAYER * DD * DD * 2);
    u16* WtOutL= (u16*)alloc((size_t)NLAYER * DD * DD * 2);
    u16* Wt1H  = (u16*)alloc((size_t)NLAYER * DD * HD * 2);
    u16* Wt1L  = (u16*)alloc((size_t)NLAYER * DD * HD * 2);
    u16* Wt2H  = (u16*)alloc((size_t)NLAYER * HD * DD * 2);
    u16* Wt2L  = (u16*)alloc((size_t)NLAYER * HD * DD * 2);

    twiddle_kernel<<<(NFFT + 255) / 256, 256, 0, stream>>>(tw);
    embed_kernel<<<(BLD + 255) / 256, 256, 0, stream>>>(ids, emb, u);
    wprep_kernel<<<dim3(TD / 64, DD / 64, NLAYER), 256, 0, stream>>>(
        Win, WtInH, WtInL, DD, TD, (long)DD * TD, (long)TD * DD);
    wprep_kernel<<<dim3(DD / 64, DD / 64, NLAYER), 256, 0, stream>>>(
        Wout, WtOutH, WtOutL, DD, DD, (long)DD * DD, (long)DD * DD);
    wprep_kernel<<<dim3(HD / 64, DD / 64, NLAYER), 256, 0, stream>>>(
        W1, Wt1H, Wt1L, DD, HD, (long)DD * HD, (long)DD * HD);
    wprep_kernel<<<dim3(DD / 64, HD / 64, NLAYER), 256, 0, stream>>>(
        W2, Wt2H, Wt2L, HD, DD, (long)HD * DD, (long)HD * DD);

    // ln1 of layer 0 (later layers get z from the fused W2+LN kernel)
    ln_kernel<1><<<BB * LL, 128, 0, stream>>>(u, zh, zl, ln1_g, ln1_b);

    for (int l = 0; l < NLAYER; l++) {
        // p = z @ Win + bin (3-pass: feeds the multiplicative gate chain)
        mfma_gemm3<0, false, 3><<<dim3(TD / 128, (BB * LL) / 128), 256, 0, stream>>>(
            zh, zl, WtInH + (size_t)l * TD * DD, WtInL + (size_t)l * TD * DD,
            bin_ + (size_t)l * TD, pf, nullptr, nullptr, BB * LL, TD, DD);

        conv_gate_kernel<<<dim3(LL / 64, DD / 64, BB), 256, 0, stream>>>(
            pf, convw + (size_t)l * TD * 3, convb + (size_t)l * TD, vg, x2s);

        hf_kernel<<<DD, 1024, 0, stream>>>(hflt + (size_t)l * DD * LL, HfA, HfB, tw);

        fftconv_kernel<<<BB * DD, 1024, 0, stream>>>(
            vg, x2s, HfA, HfB, Db + (size_t)l * DD, tw, yg);

        ytr_kernel<<<dim3(LL / 64, DD / 64, BB), 256, 0, stream>>>(yg, yh, yl);

        // u += y @ Wout + bout ; z = ln2(u)   (fused, 2-pass)
        gemm_ln_kernel<1><<<(BB * LL) / 64, 512, 0, stream>>>(
            yh, yl, WtOutH + (size_t)l * DD * DD, bout + (size_t)l * DD,
            u, zh, zl, ln2_g + (size_t)l * DD, ln2_b + (size_t)l * DD, DD);

        // hmid = gelu(z @ W1 + b1) (2-pass)
        mfma_gemm3<1, true, 2><<<dim3(HD / 128, (BB * LL) / 128), 256, 0, stream>>>(
            zh, zl, Wt1H + (size_t)l * DD * HD, Wt1L + (size_t)l * DD * HD,
            b1 + (size_t)l * HD, nullptr, hmh, hml, BB * LL, HD, DD);

        // u += hmid @ W2 + b2 ; z = ln1(u) of next layer, or final lnf
        if (l < NLAYER - 1) {
            gemm_ln_kernel<1><<<(BB * LL) / 64, 512, 0, stream>>>(
                hmh, hml, Wt2H + (size_t)l * HD * DD, b2 + (size_t)l * DD,
                u, zh, zl, ln1_g + (size_t)(l + 1) * DD, ln1_b + (size_t)(l + 1) * DD, HD);
        } else {
            gemm_ln_kernel<0><<<(BB * LL) / 64, 512, 0, stream>>>(
                hmh, hml, Wt2H + (size_t)l * HD * DD, b2 + (size_t)l * DD,
                u, d_out, nullptr, lnf_g, lnf_b, HD);
        }
    }
}

// Round 15
// 4728.610 us; speedup vs baseline: 1.0785x; 1.0785x over previous
//
#include <hip/hip_runtime.h>
#include <hip/hip_bf16.h>
#include <math.h>

#define BB 2
#define LL 8192
#define DD 512
#define NLAYER 8
#define TD 1536   // 3*D
#define HD 2048   // 4*D
#define NFFT 16384
#define NHALF 8192
#define HSTR 4160  // padded length of stored half-spectrum (k in [0,4096])
#define BLD (BB*LL*DD)
#define BLH ((size_t)BB*LL*HD)

typedef unsigned short u16;
typedef unsigned int   u32;
typedef __bf16 bf16x8 __attribute__((ext_vector_type(8)));
typedef float  f32x4  __attribute__((ext_vector_type(4)));

__device__ __forceinline__ u16 f2bf(float f) {
    union { float f; u32 u; } v; v.f = f;
    u32 r = v.u + 0x7FFF + ((v.u >> 16) & 1);   // RNE
    return (u16)(r >> 16);
}
__device__ __forceinline__ float bf2f(u16 h) {
    union { u32 u; float f; } v; v.u = (u32)h << 16; return v.f;
}

__device__ __forceinline__ void async_g2l_16(const u16* g, u16* l) {
    __builtin_amdgcn_global_load_lds(
        (const __attribute__((address_space(1))) void*)g,
        (__attribute__((address_space(3))) void*)l,
        16, 0, 0);
}

__device__ __forceinline__ float2 cmul(float2 a, float2 b) {
    return make_float2(a.x * b.x - a.y * b.y, a.x * b.y + a.y * b.x);
}
__device__ __forceinline__ float2 cmulc(float2 a, float2 b) {  // a*conj(b)
    return make_float2(a.x * b.x + a.y * b.y, a.y * b.x - a.x * b.y);
}
__device__ __forceinline__ float2 cadd(float2 a, float2 b) {
    return make_float2(a.x + b.x, a.y + b.y);
}
__device__ __forceinline__ float2 csub(float2 a, float2 b) {
    return make_float2(a.x - b.x, a.y - b.y);
}
// reverse 6 base-4 digits of a 12-bit index
__device__ __forceinline__ int drev12(int m) {
    return ((m & 3) << 10) | (((m >> 2) & 3) << 8) | (((m >> 4) & 3) << 6) |
           (((m >> 6) & 3) << 4) | (((m >> 8) & 3) << 2) | ((m >> 10) & 3);
}
// frequency k (0..8191) -> LDS position after fwd FFT (r2-DIF + 6 r4-DIF per half)
__device__ __forceinline__ int perm8k(int k) {
    return ((k & 1) << 12) + drev12(k >> 1);
}
// LDS bank swizzle (float2 elements): XOR low 4 bits with hash of high bits.
__device__ __forceinline__ int swz(int i) {
    return i ^ (((i >> 4) ^ (i >> 8)) & 15);
}
#define LDX(arr, i) arr[swz(i)]

// ---------------- twiddle table: tw[k] = exp(-2*pi*i*k/NFFT), k in [0,N) ----
__global__ void twiddle_kernel(float* twf) {
    int k = blockIdx.x * 256 + threadIdx.x;
    if (k < NFFT) {
        double ang = -2.0 * M_PI * (double)k / (double)NFFT;
        twf[2 * k]     = (float)cos(ang);
        twf[2 * k + 1] = (float)sin(ang);
    }
}

// ---------------- embedding ------------------------------------------------
__global__ void embed_kernel(const int* __restrict__ ids,
                             const float* __restrict__ emb,
                             float* __restrict__ u) {
    int i = blockIdx.x * 256 + threadIdx.x;
    if (i < BLD) {
        int row = i >> 9;
        int d   = i & (DD - 1);
        u[i] = emb[ids[row] * DD + d];
    }
}

// ------------- weight prep: f32 [K,N] -> bf16 hi/lo [N,K] -------------------
__global__ __launch_bounds__(256)
void wprep_kernel(const float* __restrict__ W, u16* __restrict__ WtH,
                  u16* __restrict__ WtL, int K, int N, long srcStride, long dstStride) {
    __shared__ float t[64][65];
    const float* src = W + (size_t)blockIdx.z * srcStride;
    u16* dsth = WtH + (size_t)blockIdx.z * dstStride;
    u16* dstl = WtL + (size_t)blockIdx.z * dstStride;
    int n0 = blockIdx.x * 64, k0 = blockIdx.y * 64;
    int tc = threadIdx.x & 63, tr = threadIdx.x >> 6;
    for (int r = tr; r < 64; r += 4)
        t[r][tc] = src[(size_t)(k0 + r) * N + n0 + tc];
    __syncthreads();
    for (int r = tr; r < 64; r += 4) {
        float v = t[tc][r];
        u16 h = f2bf(v);
        dsth[(size_t)(n0 + r) * K + k0 + tc] = h;
        dstl[(size_t)(n0 + r) * K + k0 + tc] = f2bf(v - bf2f(h));
    }
}

// ---------------- layernorm (row length 512), 2 rows per 256-thr block -----
// Per-row math identical to the single-row version (bit-exact): each row has
// its own 128 threads (2 waves) and its own reduction slots.
template<int MODE>   // 0: f32 out. 1: bf16 hi/lo planes.
__global__ __launch_bounds__(256)
void ln_kernel(const float* __restrict__ x, void* __restrict__ out,
               void* __restrict__ outL,
               const float* __restrict__ g, const float* __restrict__ b) {
    int r2 = threadIdx.x >> 7;          // row within block (0/1)
    int t  = threadIdx.x & 127;         // thread within row
    int row = blockIdx.x * 2 + r2;
    const float4* xr = (const float4*)(x + (size_t)row * DD);
    float4 v = xr[t];
    float s  = v.x + v.y + v.z + v.w;
    float ss = v.x * v.x + v.y * v.y + v.z * v.z + v.w * v.w;
    for (int off = 32; off; off >>= 1) {
        s  += __shfl_down(s, off);
        ss += __shfl_down(ss, off);
    }
    __shared__ float sm[2][4];
    if ((t & 63) == 0) { sm[r2][(t >> 6) * 2] = s; sm[r2][(t >> 6) * 2 + 1] = ss; }
    __syncthreads();
    float S = sm[r2][0] + sm[r2][2], SS = sm[r2][1] + sm[r2][3];
    float mu  = S * (1.0f / DD);
    float var = SS * (1.0f / DD) - mu * mu;
    float rs  = rsqrtf(var + 1e-5f);
    float4 gg = ((const float4*)g)[t];
    float4 bb = ((const float4*)b)[t];
    float o[4];
    o[0] = (v.x - mu) * rs * gg.x + bb.x;
    o[1] = (v.y - mu) * rs * gg.y + bb.y;
    o[2] = (v.z - mu) * rs * gg.z + bb.z;
    o[3] = (v.w - mu) * rs * gg.w + bb.w;
    if (MODE == 1) {
        u16 h[4], lo[4];
#pragma unroll
        for (int i = 0; i < 4; i++) {
            h[i]  = f2bf(o[i]);
            lo[i] = f2bf(o[i] - bf2f(h[i]));
        }
        uint2 ph, pl;
        ph.x = (u32)h[0] | ((u32)h[1] << 16);  ph.y = (u32)h[2] | ((u32)h[3] << 16);
        pl.x = (u32)lo[0] | ((u32)lo[1] << 16); pl.y = (u32)lo[2] | ((u32)lo[3] << 16);
        ((uint2*)((u16*)out  + (size_t)row * DD))[t] = ph;
        ((uint2*)((u16*)outL + (size_t)row * DD))[t] = pl;
    } else {
        float4 of = {o[0], o[1], o[2], o[3]};
        ((float4*)((float*)out + (size_t)row * DD))[t] = of;
    }
}

// ---------------- gelu (tanh approximation, JAX default) -------------------
__device__ __forceinline__ float gelu_f(float x) {
    float x3 = x * x * x;
    float t  = tanhf(0.79788456080286541f * (x + 0.044715f * x3));
    return 0.5f * x * (1.0f + t);
}

// ------- compensated bf16 MFMA GEMM: C = (Ah+Al) @ (Bh+Bl)^T + bias --------
// PASSES=3: ah*bh + al*bh + ah*bl.  PASSES=2: ah*bh + al*bh.
// XCD-aware block swizzle (T1): contiguous tile chunks per XCD for L2 reuse.
template<int OUT, bool GELU, int PASSES>  // OUT 0: f32 store. 1: bf16 hi/lo. 2: f32 accum.
__global__ __launch_bounds__(256)
void mfma_gemm3(const u16* __restrict__ Ah, const u16* __restrict__ Al,
                const u16* __restrict__ Bh, const u16* __restrict__ Bl,
                const float* __restrict__ bias,
                float* __restrict__ Cf, u16* __restrict__ Ch, u16* __restrict__ Cl,
                int M, int N, int K) {
    __shared__ u16 AsH[128 * 32];
    __shared__ u16 AsL[128 * 32];
    __shared__ u16 BsH[128 * 32];
    __shared__ u16 BsL[(PASSES == 3) ? 128 * 32 : 8];
    int nwg  = gridDim.x * gridDim.y;
    int wgid = blockIdx.y * gridDim.x + blockIdx.x;
    int nid  = (wgid & 7) * (nwg >> 3) + (wgid >> 3);
    int bx = nid % gridDim.x, by = nid / gridDim.x;
    int m0 = by * 128, n0 = bx * 128;
    int tid = threadIdx.x;
    int w = tid >> 6, l = tid & 63;
    int wr = w >> 1, wc = w & 1;

    int ch0 = w * 2, ch1 = ch0 + 1;
    size_t offA0 = (size_t)(m0 + ch0 * 16 + (l >> 2)) * K + (l & 3) * 8;
    size_t offA1 = (size_t)(m0 + ch1 * 16 + (l >> 2)) * K + (l & 3) * 8;
    size_t offB0 = (size_t)(n0 + ch0 * 16 + (l >> 2)) * K + (l & 3) * 8;
    size_t offB1 = (size_t)(n0 + ch1 * 16 + (l >> 2)) * K + (l & 3) * 8;

    f32x4 acc[4][4] = {};
    int arow = wr * 64 + (l & 15);
    int brow = wc * 64 + (l & 15);
    int kc   = (l >> 4) * 8;

    for (int k0 = 0; k0 < K; k0 += 32) {
        async_g2l_16(Ah + offA0 + k0, &AsH[ch0 * 512]);
        async_g2l_16(Ah + offA1 + k0, &AsH[ch1 * 512]);
        async_g2l_16(Al + offA0 + k0, &AsL[ch0 * 512]);
        async_g2l_16(Al + offA1 + k0, &AsL[ch1 * 512]);
        async_g2l_16(Bh + offB0 + k0, &BsH[ch0 * 512]);
        async_g2l_16(Bh + offB1 + k0, &BsH[ch1 * 512]);
        if (PASSES == 3) {
            async_g2l_16(Bl + offB0 + k0, &BsL[ch0 * 512]);
            async_g2l_16(Bl + offB1 + k0, &BsL[ch1 * 512]);
        }
        __syncthreads();
        bf16x8 ah[4], al[4], bh[4], bl[4];
#pragma unroll
        for (int i = 0; i < 4; i++) {
            ah[i] = *(const bf16x8*)&AsH[(arow + i * 16) * 32 + kc];
            al[i] = *(const bf16x8*)&AsL[(arow + i * 16) * 32 + kc];
            bh[i] = *(const bf16x8*)&BsH[(brow + i * 16) * 32 + kc];
            if (PASSES == 3)
                bl[i] = *(const bf16x8*)&BsL[(brow + i * 16) * 32 + kc];
        }
#pragma unroll
        for (int mi = 0; mi < 4; mi++)
#pragma unroll
            for (int ni = 0; ni < 4; ni++) {
                acc[mi][ni] = __builtin_amdgcn_mfma_f32_16x16x32_bf16(
                    ah[mi], bh[ni], acc[mi][ni], 0, 0, 0);
                acc[mi][ni] = __builtin_amdgcn_mfma_f32_16x16x32_bf16(
                    al[mi], bh[ni], acc[mi][ni], 0, 0, 0);
                if (PASSES == 3)
                    acc[mi][ni] = __builtin_amdgcn_mfma_f32_16x16x32_bf16(
                        ah[mi], bl[ni], acc[mi][ni], 0, 0, 0);
            }
        __syncthreads();
    }

    int lr = l >> 4, lc = l & 15;
#pragma unroll
    for (int mi = 0; mi < 4; mi++) {
#pragma unroll
        for (int ni = 0; ni < 4; ni++) {
            int col = n0 + wc * 64 + ni * 16 + lc;
            float bv = bias[col];
            int rowb = m0 + wr * 64 + mi * 16 + lr * 4;
#pragma unroll
            for (int r = 0; r < 4; r++) {
                float v = acc[mi][ni][r] + bv;
                if (GELU) v = gelu_f(v);
                size_t off = (size_t)(rowb + r) * N + col;
                if (OUT == 0) {
                    Cf[off] = v;
                } else if (OUT == 1) {
                    u16 h = f2bf(v);
                    Ch[off] = h;
                    Cl[off] = f2bf(v - bf2f(h));
                } else {
                    Cf[off] += v;
                }
            }
        }
    }
}

// ---------------- short conv (k=3 causal) + gating + transpose -------------
__global__ __launch_bounds__(256)
void conv_gate_kernel(const float* __restrict__ p, const float* __restrict__ cw,
                      const float* __restrict__ cb, float* __restrict__ vg,
                      float* __restrict__ x2s) {
    __shared__ float tvg[64][65];
    __shared__ float tx2[64][65];
    int b = blockIdx.z, c0 = blockIdx.y * 64, l0 = blockIdx.x * 64;
    int tc = threadIdx.x & 63, tr = threadIdx.x >> 6;
    const float* pb = p + (size_t)b * LL * TD;
    int cx2 = c0 + tc;
    int cx1 = DD + c0 + tc;
    int cv  = 2 * DD + c0 + tc;
    float w20 = cw[cx2 * 3], w21 = cw[cx2 * 3 + 1], w22 = cw[cx2 * 3 + 2], bx2 = cb[cx2];
    float w10 = cw[cx1 * 3], w11 = cw[cx1 * 3 + 1], w12 = cw[cx1 * 3 + 2], bx1 = cb[cx1];
    float wv0 = cw[cv * 3],  wv1 = cw[cv * 3 + 1],  wv2 = cw[cv * 3 + 2],  bv  = cb[cv];
    for (int r = tr; r < 64; r += 4) {
        int l = l0 + r;
        size_t o0 = (size_t)l * TD;
        float p2a = (l >= 2) ? pb[o0 - 2 * TD + cx2] : 0.f;
        float p1a = (l >= 1) ? pb[o0 - TD + cx2] : 0.f;
        float p0a = pb[o0 + cx2];
        float p2b = (l >= 2) ? pb[o0 - 2 * TD + cx1] : 0.f;
        float p1b = (l >= 1) ? pb[o0 - TD + cx1] : 0.f;
        float p0b = pb[o0 + cx1];
        float p2c = (l >= 2) ? pb[o0 - 2 * TD + cv] : 0.f;
        float p1c = (l >= 1) ? pb[o0 - TD + cv] : 0.f;
        float p0c = pb[o0 + cv];
        float x2v = w20 * p2a + w21 * p1a + w22 * p0a + bx2;
        float x1v = w10 * p2b + w11 * p1b + w12 * p0b + bx1;
        float vv  = wv0 * p2c + wv1 * p1c + wv2 * p0c + bv;
        tx2[r][tc] = x2v;
        tvg[r][tc] = vv * x1v;
    }
    __syncthreads();
    for (int r = tr; r < 64; r += 4) {
        size_t o = ((size_t)b * DD + c0 + r) * LL + l0 + tc;
        vg[o]  = tvg[tc][r];
        x2s[o] = tx2[tc][r];
    }
}

// -------- y transpose: f32 [B,D,L] -> bf16 hi/lo [B*L, D] ------------------
__global__ __launch_bounds__(256)
void ytr_kernel(const float* __restrict__ yg, u16* __restrict__ yh,
                u16* __restrict__ yl) {
    __shared__ float t[64][65];
    int b = blockIdx.z, c0 = blockIdx.y * 64, l0 = blockIdx.x * 64;
    int tc = threadIdx.x & 63, tr = threadIdx.x >> 6;
    for (int r = tr; r < 64; r += 4)
        t[r][tc] = yg[((size_t)b * DD + c0 + r) * LL + l0 + tc];
    __syncthreads();
    for (int r = tr; r < 64; r += 4) {
        float v = t[tc][r];
        u16 h = f2bf(v);
        size_t o = ((size_t)(b * LL + l0 + r)) * DD + c0 + tc;
        yh[o] = h;
        yl[o] = f2bf(v - bf2f(h));
    }
}

// ======== 8192-pt complex FFT in 64 KiB LDS (r2c half-length core) =========
__device__ __forceinline__ void fft8192_fwd(float2* ld, const float2* __restrict__ tw, int tid) {
    __syncthreads();
    for (int n = tid; n < 4096; n += 1024) {
        float2 a = LDX(ld, n), b = LDX(ld, n + 4096);
        LDX(ld, n) = cadd(a, b);
        float2 d = csub(a, b);
        LDX(ld, n + 4096) = n ? cmul(d, tw[2 * n]) : d;   // tw8192[n] = tw[2n]
    }
    for (int s = 0; s < 6; s++) {
        int lm = 12 - 2 * s, lq = lm - 2;
        int Q = 1 << lq;
        __syncthreads();
        for (int g = tid; g < 2048; g += 1024) {
            int half = g >> 10, gg = g & 1023;
            int j = gg & (Q - 1);
            int base = (half << 12) + ((gg >> lq) << lm) + j;
            float2 x0 = LDX(ld, base), x1 = LDX(ld, base + Q);
            float2 x2 = LDX(ld, base + 2 * Q), x3 = LDX(ld, base + 3 * Q);
            float2 a = cadd(x0, x2), b = csub(x0, x2);
            float2 c = cadd(x1, x3), d = csub(x1, x3);
            float2 mid = make_float2(d.y, -d.x);          // -i*d
            float2 u0 = cadd(a, c);
            float2 u1 = cadd(b, mid);
            float2 u2 = csub(a, c);
            float2 u3 = csub(b, mid);
            int e = j << (2 * s);                          // relative to N'=4096
            if (e) {                                       // tw4096[e] = tw[4e]
                u1 = cmul(u1, tw[4 * e]);
                u2 = cmul(u2, tw[8 * e]);
                u3 = cmul(u3, tw[12 * e]);
            }
            LDX(ld, base) = u0; LDX(ld, base + Q) = u1;
            LDX(ld, base + 2 * Q) = u2; LDX(ld, base + 3 * Q) = u3;
        }
    }
    __syncthreads();
}

__device__ __forceinline__ void fft8192_inv(float2* ld, const float2* __restrict__ tw, int tid) {
    for (int s = 5; s >= 0; s--) {
        int lm = 12 - 2 * s, lq = lm - 2;
        int Q = 1 << lq;
        __syncthreads();
        for (int g = tid; g < 2048; g += 1024) {
            int half = g >> 10, gg = g & 1023;
            int j = gg & (Q - 1);
            int base = (half << 12) + ((gg >> lq) << lm) + j;
            int e = j << (2 * s);
            float2 v0 = LDX(ld, base);
            float2 v1 = LDX(ld, base + Q), v2 = LDX(ld, base + 2 * Q), v3 = LDX(ld, base + 3 * Q);
            if (e) {
                v1 = cmulc(v1, tw[4 * e]);
                v2 = cmulc(v2, tw[8 * e]);
                v3 = cmulc(v3, tw[12 * e]);
            }
            float2 a = cadd(v0, v2), b = csub(v0, v2);
            float2 c = cadd(v1, v3), d = csub(v1, v3);
            float2 id = make_float2(-d.y, d.x);           // +i*d
            LDX(ld, base)         = cadd(a, c);
            LDX(ld, base + Q)     = cadd(b, id);
            LDX(ld, base + 2 * Q) = csub(a, c);
            LDX(ld, base + 3 * Q) = csub(b, id);
        }
    }
    __syncthreads();
    for (int n = tid; n < 4096; n += 1024) {
        float2 a = LDX(ld, n);
        float2 b = LDX(ld, n + 4096);
        if (n) b = cmulc(b, tw[2 * n]);
        LDX(ld, n) = cadd(a, b);
        LDX(ld, n + 4096) = csub(a, b);
    }
    __syncthreads();
}

// -------- filter FFT (r2c): store only k in [0,4096] of Ha=H[k], Hb=H[k+8192]
__global__ __launch_bounds__(1024, 8)
void hf_kernel(const float* __restrict__ h, float2* __restrict__ HfA,
               float2* __restrict__ HfB, const float* __restrict__ twf) {
    __shared__ float2 ld[NHALF];  // 64 KiB -> 2 blocks/CU
    int c = blockIdx.x;
    const float2* hp = (const float2*)(h + (size_t)c * LL);
    const float2* tw = (const float2*)twf;
    int tid = threadIdx.x;
    for (int n = tid; n < 4096; n += 1024) LDX(ld, n) = hp[n];     // z = h[2n]+i*h[2n+1]
    for (int n = 4096 + tid; n < NHALF; n += 1024) LDX(ld, n) = make_float2(0.f, 0.f);
    fft8192_fwd(ld, tw, tid);
    float2* oa = HfA + (size_t)c * HSTR;
    float2* ob = HfB + (size_t)c * HSTR;
    for (int k = tid; k <= 4096; k += 1024) {
        int kc = (NHALF - k) & (NHALF - 1);
        int p = perm8k(k), pc = perm8k(kc);
        float2 A = LDX(ld, p), B = LDX(ld, pc);
        float2 E = make_float2(0.5f * (A.x + B.x), 0.5f * (A.y - B.y));
        float2 O = make_float2(0.5f * (A.y + B.y), -0.5f * (A.x - B.x));
        float2 t = tw[k];
        float2 tO = cmul(t, O);
        oa[k] = cadd(E, tO);   // H[k]
        ob[k] = csub(E, tO);   // H[k+8192]
    }
}

// ------- FFT convolution (r2c), 1 channel/block + skip + output gate -------
__global__ __launch_bounds__(1024, 8)
void fftconv_kernel(const float* __restrict__ vg, const float* __restrict__ x2s,
                    const float2* __restrict__ HfA, const float2* __restrict__ HfB,
                    const float* __restrict__ Db, const float* __restrict__ twf,
                    float* __restrict__ yg) {
    __shared__ float2 ld[NHALF];  // 64 KiB -> 2 blocks/CU
    int bc = blockIdx.x;                  // b * DD + c
    int c  = bc & (DD - 1);
    const float2* vp  = (const float2*)(vg  + (size_t)bc * LL);
    const float2* x2p = (const float2*)(x2s + (size_t)bc * LL);
    float2*       op  = (float2*)(yg + (size_t)bc * LL);
    const float2* tw = (const float2*)twf;
    int tid = threadIdx.x;
    float2 vv[4];
#pragma unroll
    for (int q = 0; q < 4; q++) {
        int n = tid + q * 1024;
        vv[q] = vp[n];
        LDX(ld, n) = vv[q];               // z = v[2n]+i*v[2n+1]
    }
#pragma unroll
    for (int q = 0; q < 4; q++) LDX(ld, tid + 4096 + q * 1024) = make_float2(0.f, 0.f);
    fft8192_fwd(ld, tw, tid);
    const float2* Ha = HfA + (size_t)c * HSTR;
    const float2* Hb = HfB + (size_t)c * HSTR;
    for (int k = tid; k <= 4096; k += 1024) {
        int kc = (NHALF - k) & (NHALF - 1);
        int p = perm8k(k), pc = perm8k(kc);
        float2 A = LDX(ld, p), B = LDX(ld, pc);
        float2 E = make_float2(0.5f * (A.x + B.x), 0.5f * (A.y - B.y));
        float2 O = make_float2(0.5f * (A.y + B.y), -0.5f * (A.x - B.x));
        float2 t = tw[k];
        float2 tO = cmul(t, O);
        float2 X1 = cadd(E, tO);           // X[k]
        float2 X2 = csub(E, tO);           // X[k+8192]
        float2 Hak = Ha[k], Hbk = Hb[k];
        float2 Y1 = cmul(X1, Hak);
        float2 Y2 = cmul(X2, Hbk);
        float2 S  = make_float2(0.5f * (Y1.x + Y2.x), 0.5f * (Y1.y + Y2.y));
        float2 Dd = make_float2(0.5f * (Y1.x - Y2.x), 0.5f * (Y1.y - Y2.y));
        // W[k] = S + i*conj(t)*Dd ;  i*conj(t) = (t.y, t.x)
        LDX(ld, p) = cadd(S, cmul(make_float2(t.y, t.x), Dd));
        if (kc != k) {
            float2 X1c = make_float2(X2.x, -X2.y);   // X[kc]      = conj(X[k+8192])
            float2 X2c = make_float2(X1.x, -X1.y);   // X[kc+8192] = conj(X[k])
            float2 Y1c = cmulc(X1c, Hbk);            // Ha[kc]=conj(Hb[k])
            float2 Y2c = cmulc(X2c, Hak);            // Hb[kc]=conj(Ha[k])
            float2 Sc = make_float2(0.5f * (Y1c.x + Y2c.x), 0.5f * (Y1c.y + Y2c.y));
            float2 Dc = make_float2(0.5f * (Y1c.x - Y2c.x), 0.5f * (Y1c.y - Y2c.y));
            // i*conj(t_kc) = -i*t = (t.y, -t.x)
            LDX(ld, pc) = cadd(Sc, cmul(make_float2(t.y, -t.x), Dc));
        }
    }
    fft8192_inv(ld, tw, tid);
    float db = Db[c];
    const float inv = 1.0f / (float)NHALF;
#pragma unroll
    for (int q = 0; q < 4; q++) {
        int n = tid + q * 1024;
        float2 w  = LDX(ld, n);
        float2 xx = x2p[n];
        float y0 = w.x * inv + vv[q].x * db;
        float y1 = w.y * inv + vv[q].y * db;
        op[n] = make_float2(y0 * xx.x, y1 * xx.y);
    }
}

// ---------------------------------------------------------------------------
extern "C" void kernel_launch(void* const* d_in, const int* in_sizes, int n_in,
                              void* d_out, int out_size, void* d_ws, size_t ws_size,
                              hipStream_t stream) {
    const int*   ids   = (const int*)  d_in[0];
    const float* emb   = (const float*)d_in[1];
    const float* ln1_g = (const float*)d_in[2];
    const float* ln1_b = (const float*)d_in[3];
    const float* Win   = (const float*)d_in[4];
    const float* bin_  = (const float*)d_in[5];
    const float* convw = (const float*)d_in[6];
    const float* convb = (const float*)d_in[7];
    const float* hflt  = (const float*)d_in[8];
    const float* Db    = (const float*)d_in[9];
    const float* Wout  = (const float*)d_in[10];
    const float* bout  = (const float*)d_in[11];
    const float* ln2_g = (const float*)d_in[12];
    const float* ln2_b = (const float*)d_in[13];
    const float* W1    = (const float*)d_in[14];
    const float* b1    = (const float*)d_in[15];
    const float* W2    = (const float*)d_in[16];
    const float* b2    = (const float*)d_in[17];
    const float* lnf_g = (const float*)d_in[18];
    const float* lnf_b = (const float*)d_in[19];

    char* p_ = (char*)d_ws;
    auto alloc = [&](size_t bytes) {
        char* r = p_; p_ += (bytes + 255) & ~(size_t)255; return r;
    };
    float* u   = (float*)alloc((size_t)BLD * 4);
    u16* zh    = (u16*)  alloc((size_t)BLD * 2);
    u16* zl    = (u16*)  alloc((size_t)BLD * 2);
    char* uni  = alloc(2 * BLH * 2);      // pf (f32 3*BLD) | yg (f32 BLD) | hmid hi/lo
    float* pf  = (float*)uni;
    float* yg  = (float*)uni;
    u16* hmh   = (u16*)uni;
    u16* hml   = hmh + BLH;
    float* vg  = (float*)alloc((size_t)BLD * 4);
    float* x2s = (float*)alloc((size_t)BLD * 4);
    u16* yh    = (u16*)  alloc((size_t)BLD * 2);
    u16* yl    = (u16*)  alloc((size_t)BLD * 2);
    float2* HfA = (float2*)alloc((size_t)DD * HSTR * 8);
    float2* HfB = (float2*)alloc((size_t)DD * HSTR * 8);
    float* tw  = (float*)alloc((size_t)2 * NFFT * 4);
    u16* WtInH = (u16*)alloc((size_t)NLAYER * TD * DD * 2);
    u16* WtInL = (u16*)alloc((size_t)NLAYER * TD * DD * 2);
    u16* WtOutH= (u16*)alloc((size_t)NLAYER * DD * DD * 2);
    u16* WtOutL= (u16*)alloc((size_t)NLAYER * DD * DD * 2);
    u16* Wt1H  = (u16*)alloc((size_t)NLAYER * DD * HD * 2);
    u16* Wt1L  = (u16*)alloc((size_t)NLAYER * DD * HD * 2);
    u16* Wt2H  = (u16*)alloc((size_t)NLAYER * HD * DD * 2);
    u16* Wt2L  = (u16*)alloc((size_t)NLAYER * HD * DD * 2);

    twiddle_kernel<<<(NFFT + 255) / 256, 256, 0, stream>>>(tw);
    embed_kernel<<<(BLD + 255) / 256, 256, 0, stream>>>(ids, emb, u);
    wprep_kernel<<<dim3(TD / 64, DD / 64, NLAYER), 256, 0, stream>>>(
        Win, WtInH, WtInL, DD, TD, (long)DD * TD, (long)TD * DD);
    wprep_kernel<<<dim3(DD / 64, DD / 64, NLAYER), 256, 0, stream>>>(
        Wout, WtOutH, WtOutL, DD, DD, (long)DD * DD, (long)DD * DD);
    wprep_kernel<<<dim3(HD / 64, DD / 64, NLAYER), 256, 0, stream>>>(
        W1, Wt1H, Wt1L, DD, HD, (long)DD * HD, (long)DD * HD);
    wprep_kernel<<<dim3(DD / 64, HD / 64, NLAYER), 256, 0, stream>>>(
        W2, Wt2H, Wt2L, HD, DD, (long)HD * DD, (long)HD * DD);

    for (int l = 0; l < NLAYER; l++) {
        ln_kernel<1><<<BB * LL / 2, 256, 0, stream>>>(u, zh, zl,
            ln1_g + l * DD, ln1_b + l * DD);

        // p = z @ Win + bin (3-pass: feeds the multiplicative gate chain)
        mfma_gemm3<0, false, 3><<<dim3(TD / 128, (BB * LL) / 128), 256, 0, stream>>>(
            zh, zl, WtInH + (size_t)l * TD * DD, WtInL + (size_t)l * TD * DD,
            bin_ + (size_t)l * TD, pf, nullptr, nullptr, BB * LL, TD, DD);

        conv_gate_kernel<<<dim3(LL / 64, DD / 64, BB), 256, 0, stream>>>(
            pf, convw + (size_t)l * TD * 3, convb + (size_t)l * TD, vg, x2s);

        hf_kernel<<<DD, 1024, 0, stream>>>(hflt + (size_t)l * DD * LL, HfA, HfB, tw);

        fftconv_kernel<<<BB * DD, 1024, 0, stream>>>(
            vg, x2s, HfA, HfB, Db + (size_t)l * DD, tw, yg);

        ytr_kernel<<<dim3(LL / 64, DD / 64, BB), 256, 0, stream>>>(yg, yh, yl);

        // u += y @ Wout + bout (2-pass)
        mfma_gemm3<2, false, 2><<<dim3(DD / 128, (BB * LL) / 128), 256, 0, stream>>>(
            yh, yl, WtOutH + (size_t)l * DD * DD, WtOutL + (size_t)l * DD * DD,
            bout + (size_t)l * DD, u, nullptr, nullptr, BB * LL, DD, DD);

        ln_kernel<1><<<BB * LL / 2, 256, 0, stream>>>(u, zh, zl,
            ln2_g + l * DD, ln2_b + l * DD);

        // hmid = gelu(z @ W1 + b1) (2-pass)
        mfma_gemm3<1, true, 2><<<dim3(HD / 128, (BB * LL) / 128), 256, 0, stream>>>(
            zh, zl, Wt1H + (size_t)l * DD * HD, Wt1L + (size_t)l * DD * HD,
            b1 + (size_t)l * HD, nullptr, hmh, hml, BB * LL, HD, DD);

        // u += hmid @ W2 + b2 (2-pass)
        mfma_gemm3<2, false, 2><<<dim3(DD / 128, (BB * LL) / 128), 256, 0, stream>>>(
            hmh, hml, Wt2H + (size_t)l * HD * DD, Wt2L + (size_t)l * HD * DD,
            b2 + (size_t)l * DD, u, nullptr, nullptr, BB * LL, DD, HD);
    }

    ln_kernel<0><<<BB * LL / 2, 256, 0, stream>>>(u, (float*)d_out, nullptr, lnf_g, lnf_b);
}